// Round 5
// baseline (5096.893 us; speedup 1.0000x reference)
//
#include <hip/hip_runtime.h>
#include <math.h>

typedef unsigned short u16; // bf16 bits
typedef short bf16x8 __attribute__((ext_vector_type(8)));
typedef float f32x4 __attribute__((ext_vector_type(4)));

__device__ __forceinline__ float bf2f(u16 u){ return __uint_as_float(((unsigned)u)<<16); }
__device__ __forceinline__ u16 f2bf(float f){
  unsigned u = __float_as_uint(f);
  u += 0x7fffu + ((u>>16)&1u);   // RNE
  return (u16)(u>>16);
}
__device__ __forceinline__ float gelu_f(float x){ return 0.5f*x*(1.0f+erff(x*0.7071067811865476f)); }

__device__ __forceinline__ float block_sum(float v, float* sh){
  #pragma unroll
  for (int o=32;o;o>>=1) v += __shfl_down(v,o,64);
  int w = threadIdx.x>>6, lane = threadIdx.x&63;
  __syncthreads();
  if (lane==0) sh[w]=v;
  __syncthreads();
  return sh[0]+sh[1]+sh[2]+sh[3];
}
__device__ __forceinline__ float block_max(float v, float* sh){
  #pragma unroll
  for (int o=32;o;o>>=1) v = fmaxf(v, __shfl_down(v,o,64));
  int w = threadIdx.x>>6, lane = threadIdx.x&63;
  __syncthreads();
  if (lane==0) sh[w]=v;
  __syncthreads();
  return fmaxf(fmaxf(sh[0],sh[1]),fmaxf(sh[2],sh[3]));
}

// load 8 consecutive elements (row-major) as bf16; F32: load f32 + convert
template<int F32>
__device__ __forceinline__ void load8(const void* ptr, long idx, u16* dst){
  if (F32){
    const float4* q = (const float4*)((const float*)ptr + idx);
    float4 a = q[0], b = q[1];
    dst[0]=f2bf(a.x); dst[1]=f2bf(a.y); dst[2]=f2bf(a.z); dst[3]=f2bf(a.w);
    dst[4]=f2bf(b.x); dst[5]=f2bf(b.y); dst[6]=f2bf(b.z); dst[7]=f2bf(b.w);
  } else {
    *(uint4*)dst = *(const uint4*)((const u16*)ptr + idx);
  }
}

// ---------------- generic MFMA GEMM, 64x64 tile, BK=32, bf16 compute -------
// C[m][n] = act( alpha * sum_k A[m][k]*B[.][.] + bias[n] )   (batched via z)
// BT=0: B is [K][N] row-major.  BT=1: B is [N][K] row-major (C = A @ B^T).
// AF32/BF32: operand stored as f32 in memory (converted to bf16 in staging).
// aadd (optional): f32 vector added to A elements along k: A[m][k] += aadd[hh*64+k]
template<int BT,int AF32,int BF32,int OF32,int ACC,int ACT>
__global__ __launch_bounds__(256) void gemm_k(
    const void* __restrict__ A, const void* __restrict__ Bm, void* __restrict__ Cv,
    const float* __restrict__ bias, const float* __restrict__ aadd,
    int M,int N,int K,int lda,int ldb,int ldc,float alpha,int z0,
    long sAz,long oAb,long oAh, long sBz,long oBb,long oBh, long sCz,long oCb,long oCh)
{
  int zz = blockIdx.z; int z = z0+zz; int bb = z>>4, hh = z&15;
  const char* Ap = (const char*)A  + ((long)zz*sAz + (long)bb*oAb + (long)hh*oAh)*(AF32?4:2);
  const char* Bp = (const char*)Bm + ((long)zz*sBz + (long)bb*oBb + (long)hh*oBh)*(BF32?4:2);
  long coff = (long)zz*sCz + (long)bb*oCb + (long)hh*oCh;
  int m0 = blockIdx.y*64, n0 = blockIdx.x*64;
  __shared__ __align__(16) u16 As[64][40];   // +8 pad (80B row, 16B-aligned)
  __shared__ __align__(16) u16 Bs[64][40];   // holds B^T tile: Bs[n][k]
  int tid = threadIdx.x;
  int w = tid>>6, lane = tid&63, q = lane>>4, m16 = lane&15;
  f32x4 acc[4] = {{0,0,0,0},{0,0,0,0},{0,0,0,0},{0,0,0,0}};
  int ar = tid>>2, ac = (tid&3)*8;          // A/B(T) staging: 64 rows x 32 cols
  int kk = tid>>3, ng = (tid&7)*8;          // B(NN) staging: 32 k-rows x 64 n

  for (int k0=0;k0<K;k0+=32){
    __syncthreads();
    u16 tmp[8];
    load8<AF32>(Ap, (long)(m0+ar)*lda + k0 + ac, tmp);
    if (aadd){
      #pragma unroll
      for (int i=0;i<8;i++) tmp[i] = f2bf(bf2f(tmp[i]) + aadd[hh*64 + k0 + ac + i]);
    }
    *(uint4*)&As[ar][ac] = *(uint4*)tmp;
    if (BT){
      load8<BF32>(Bp, (long)(n0+ar)*ldb + k0 + ac, tmp);
      *(uint4*)&Bs[ar][ac] = *(uint4*)tmp;
    } else {
      load8<BF32>(Bp, (long)(k0+kk)*ldb + n0 + ng, tmp);
      #pragma unroll
      for (int i=0;i<8;i++) Bs[ng+i][kk] = tmp[i];   // transpose into LDS
    }
    __syncthreads();
    bf16x8 af = *(const bf16x8*)&As[w*16+m16][q*8];
    #pragma unroll
    for (int j=0;j<4;j++){
      bf16x8 bfr = *(const bf16x8*)&Bs[j*16+m16][q*8];
      acc[j] = __builtin_amdgcn_mfma_f32_16x16x32_bf16(af, bfr, acc[j], 0,0,0);
    }
  }
  #pragma unroll
  for (int j=0;j<4;j++){
    int n = n0 + j*16 + m16;
    float bv = bias ? bias[n] : 0.0f;
    #pragma unroll
    for (int r=0;r<4;r++){
      int m = m0 + w*16 + q*4 + r;           // C/D: col=lane&15, row=quad*4+reg
      float v = acc[j][r]*alpha + bv;
      if (ACT==1) v = gelu_f(v);
      long ci = coff + (long)m*ldc + n;
      if (OF32){
        float* C = (float*)Cv;
        if (ACC) C[ci] += v; else C[ci] = v;
      } else {
        ((u16*)Cv)[ci] = f2bf(v);
      }
    }
  }
}

// ---------------- LayerNorm (row over D=1024), f32 in, f32 stats -----------
// out = (x-m)*rstd*g + (b? b:0); b==nullptr -> no beta (folded elsewhere)
template<int ACCXC,int HAS_OUT,int OUTF32>
__global__ __launch_bounds__(256) void ln_k(const float* __restrict__ in,
    const float* __restrict__ g, const float* __restrict__ b,
    float* __restrict__ xc, void* __restrict__ out)
{
  __shared__ float sh[4];
  long row = blockIdx.x;
  int tid = threadIdx.x;
  float x[4];
  #pragma unroll
  for (int i=0;i<4;i++) x[i] = in[row*1024 + tid + 256*i];
  float s = x[0]+x[1]+x[2]+x[3];
  float mean = block_sum(s, sh) * (1.0f/1024.0f);
  float ss = 0.f;
  #pragma unroll
  for (int i=0;i<4;i++){ float d = x[i]-mean; ss += d*d; }
  float var = block_sum(ss, sh) * (1.0f/1024.0f);
  float rstd = rsqrtf(var + 1e-5f);
  #pragma unroll
  for (int i=0;i<4;i++){
    int col = tid + 256*i;
    long idx = row*1024 + col;
    float val = (x[i]-mean)*rstd*g[col];
    if (b) val += b[col];
    if (ACCXC) xc[idx] += val;
    if (HAS_OUT){
      if (OUTF32) ((float*)out)[idx] = val;
      else ((u16*)out)[idx] = f2bf(val);
    }
  }
}

// softmax over a 1024-wide f32 score row; write (+) or subtract (-) into bf16 P
template<int SIGN>
__global__ __launch_bounds__(256) void softmax_k(const float* __restrict__ S, u16* __restrict__ P){
  __shared__ float sh[4];
  long zz = blockIdx.y, q = blockIdx.x;
  const float* srow = S + zz*1048576 + q*1024;
  u16* prow = P + zz*1048576 + q*1024;
  int tid = threadIdx.x;
  float x[4];
  #pragma unroll
  for (int i=0;i<4;i++) x[i] = srow[tid+256*i];
  float m = fmaxf(fmaxf(x[0],x[1]),fmaxf(x[2],x[3]));
  m = block_max(m, sh);
  float e[4]; float s = 0.f;
  #pragma unroll
  for (int i=0;i<4;i++){ e[i] = expf(x[i]-m); s += e[i]; }
  s = block_sum(s, sh);
  float inv = 1.0f/s;
  #pragma unroll
  for (int i=0;i<4;i++){
    int col = tid+256*i;
    float val = e[i]*inv;
    if (SIGN>0) prow[col] = f2bf(val);
    else { float o = bf2f(prow[col]); prow[col] = f2bf(o-val); }
  }
}

__global__ void cvt_k(const float* __restrict__ x, float* __restrict__ xc){
  long i = (long)blockIdx.x*256 + threadIdx.x;
  xc[i] = x[i];
}

// vavgT[z=(b,h)][dh][s] = 0.5*(v1'+v2')  (qkv hold primed/centered values)
__global__ void vavg_k(const u16* __restrict__ qkv1, const u16* __restrict__ qkv2,
                       u16* __restrict__ vavgT){
  long idx = (long)blockIdx.x*256 + threadIdx.x;
  int s  = idx & 1023;
  int dh = (idx>>10)&63;
  int h  = (idx>>16)&15;
  int b  = (int)(idx>>20);
  long off = ((long)(b*1024+s))*3072 + 2048 + h*64 + dh;
  float v = 0.5f*(bf2f(qkv1[off]) + bf2f(qkv2[off]));
  vavgT[idx] = f2bf(v);
}

// abar[d] = b1[d] + sigma_l * sum_r U[d][r] * (sum_j V[r][j])   (f32, exact)
__global__ void abar_k(const float* __restrict__ sig, const float* __restrict__ U,
                       const float* __restrict__ V, const float* __restrict__ b1,
                       float* __restrict__ abar){
  __shared__ float vs[4];
  int tid = threadIdx.x, w = tid>>6, lane = tid&63;
  float p = 0.f;
  #pragma unroll
  for (int i=0;i<16;i++) p += V[w*1024 + lane + 64*i];
  #pragma unroll
  for (int o=32;o;o>>=1) p += __shfl_down(p,o,64);
  if (lane==0) vs[w] = p;
  __syncthreads();
  float sg = sig[0];
  for (int d=tid; d<1024; d+=256){
    float a = 0.f;
    #pragma unroll
    for (int r=0;r<4;r++) a += U[d*4+r]*vs[r];
    abar[d] = b1[d] + sg*a;
  }
}

// x1bar[n] = bp1[n] + sum_{k<512} abar[k]*Wp1[k][n];  x2bar likewise (abar[512+k])
__global__ void bar1_k(const float* __restrict__ abar,
                       const float* __restrict__ Wp1, const float* __restrict__ bp1,
                       const float* __restrict__ Wp2, const float* __restrict__ bp2,
                       float* __restrict__ x1bar, float* __restrict__ x2bar){
  int n = blockIdx.x*256 + threadIdx.x;
  float s1 = bp1[n], s2 = bp2[n];
  for (int k=0;k<512;k++){
    s1 += abar[k]     * Wp1[(long)k*1024 + n];
    s2 += abar[512+k] * Wp2[(long)k*1024 + n];
  }
  x1bar[n] = s1; x2bar[n] = s2;
}

// qbar[n] = sum_{k<1024} xbar[k]*Wqkv[k][n]  (q columns only, n<1024)
__global__ void bar2_k(const float* __restrict__ xbar, const float* __restrict__ Wq,
                       float* __restrict__ qbar){
  int n = blockIdx.x*256 + threadIdx.x;
  float s = 0.f;
  for (int k=0;k<1024;k++) s += xbar[k]*Wq[(long)k*3072 + n];
  qbar[n] = s;
}

extern "C" void kernel_launch(void* const* d_in, const int* in_sizes, int n_in,
                              void* d_out, int out_size, void* d_ws, size_t ws_size,
                              hipStream_t stream){
  const float* X    = (const float*)d_in[0];
  const float* SIG  = (const float*)d_in[1];
  const float* U    = (const float*)d_in[2];
  const float* V    = (const float*)d_in[3];
  const float* Wqkv1= (const float*)d_in[4];
  const float* Wqkv2= (const float*)d_in[5];
  const float* Wp1  = (const float*)d_in[6];
  const float* bp1  = (const float*)d_in[7];
  const float* Wp2  = (const float*)d_in[8];
  const float* bp2  = (const float*)d_in[9];
  const float* Wo   = (const float*)d_in[10];
  const float* bo   = (const float*)d_in[11];
  const float* gO   = (const float*)d_in[12];
  const float* bO   = (const float*)d_in[13];
  const float* g1   = (const float*)d_in[14];
  const float* b1   = (const float*)d_in[15];
  const float* g2   = (const float*)d_in[16];
  const float* b2   = (const float*)d_in[17];
  const float* Wm1  = (const float*)d_in[18];
  const float* bm1  = (const float*)d_in[19];
  const float* Wm2  = (const float*)d_in[20];
  const float* bm2  = (const float*)d_in[21];
  const float* gf   = (const float*)d_in[22];
  const float* bfv  = (const float*)d_in[23];
  (void)in_sizes; (void)n_in; (void)out_size; (void)ws_size;

  // ---- workspace layout with aliasing (total ~68 MiB) ----
  char* p = (char*)d_ws;
  float* xc     = (float*)(p + 0);         // [0, 8M)   residual stream f32
  u16* qkv1     = (u16*)(p + 8388608);     // [8M, 20M)  bf16 (primed: no mean part)
  u16* qkv2     = (u16*)(p + 20971520);    // [20M, 32M) bf16
  u16* bufA     = (u16*)(p + 33554432);    // [32M, 36M) a_bf / attnout / h2
  u16* bufB     = (u16*)(p + 37748736);    // [36M, 40M) x1w
  u16* bufC     = (u16*)(p + 41943040);    // [40M, 44M) x2w / vavgT
  float* Sbuf   = (float*)(p + 46137344);  // [44M, 60M) 4 z-slices x 1Mi f32
  u16* mid      = (u16*)(p + 46137344);    //   aliases Sbuf (disjoint in time)
  float* projout= (float*)(p + 46137344);  //   aliases Sbuf (disjoint in time)
  u16* Pbf      = (u16*)(p + 62914560);    // [60M, 68M) 4 z-slices x 1Mi bf16
  float* abar   = (float*)(p + 71303168);  // [68M) +4KB
  float* x1bar  = (float*)(p + 71307264);
  float* x2bar  = (float*)(p + 71311360);
  float* qbar1  = (float*)(p + 71315456);
  float* qbar2  = (float*)(p + 71319552);

  u16* a_bf    = bufA; u16* attnout = bufA; u16* h2 = bufA;
  u16* x1w     = bufB;
  u16* x2w     = bufC; u16* vavgT   = bufC;

  const float SCALE = 0.125f;
  const long Z0=0;

  cvt_k<<<8192,256,0,stream>>>(X, xc);
  for (int l=0;l<4;l++){
    // exact f32 constant ("mean") path: abar = b1 + adapt; x{1,2}bar; qbar{1,2}
    abar_k<<<1,256,0,stream>>>(SIG+l, U+(long)l*4096, V+(long)l*4096, b1+l*1024, abar);
    bar1_k<<<4,256,0,stream>>>(abar, Wp1+(long)l*524288, bp1+l*1024,
                               Wp2+(long)l*524288, bp2+l*1024, x1bar, x2bar);
    bar2_k<<<4,256,0,stream>>>(x1bar, Wqkv1+(long)l*3145728, qbar1);
    bar2_k<<<4,256,0,stream>>>(x2bar, Wqkv2+(long)l*3145728, qbar2);
    // centered path: a' = LN(xc)*g1 (no beta, no adapt) -> bf16
    ln_k<0,1,0><<<2048,256,0,stream>>>(xc, g1+l*1024, nullptr, nullptr, a_bf);
    // x1' = a'[:, :512] @ Wp1 ;  x2' = a'[:, 512:] @ Wp2   (bias folded into bars)
    gemm_k<0,0,1,0,0,0><<<dim3(16,32,1),256,0,stream>>>(a_bf,     Wp1+(long)l*524288, x1w, nullptr, nullptr,
        2048,1024,512, 1024,1024,1024, 1.0f, 0, Z0,0,0, 0,0,0, 0,0,0);
    gemm_k<0,0,1,0,0,0><<<dim3(16,32,1),256,0,stream>>>(a_bf+512, Wp2+(long)l*524288, x2w, nullptr, nullptr,
        2048,1024,512, 1024,1024,1024, 1.0f, 0, Z0,0,0, 0,0,0, 0,0,0);
    // qkv' = x' @ Wqkv
    gemm_k<0,0,1,0,0,0><<<dim3(48,32,1),256,0,stream>>>(x1w, Wqkv1+(long)l*3145728, qkv1, nullptr, nullptr,
        2048,3072,1024, 1024,3072,3072, 1.0f, 0, Z0,0,0, 0,0,0, 0,0,0);
    gemm_k<0,0,1,0,0,0><<<dim3(48,32,1),256,0,stream>>>(x2w, Wqkv2+(long)l*3145728, qkv2, nullptr, nullptr,
        2048,3072,1024, 1024,3072,3072, 1.0f, 0, Z0,0,0, 0,0,0, 0,0,0);
    vavg_k<<<8192,256,0,stream>>>(qkv1,qkv2,vavgT);
    // attention in 8 chunks of 4 (b,h) batches
    // S_eff = (Q'+qbar) @ K'^T  (row-constant terms dropped: softmax-invariant)
    for (int zc=0;zc<8;zc++){
      int z0 = zc*4;
      gemm_k<1,0,0,1,0,0><<<dim3(16,16,4),256,0,stream>>>(qkv1, qkv1+1024, Sbuf, nullptr, qbar1,
          1024,1024,64, 3072,3072,1024, SCALE, z0, Z0,3145728,64, 0,3145728,64, 1048576,0,0);
      softmax_k<1><<<dim3(1024,4),256,0,stream>>>(Sbuf,Pbf);
      gemm_k<1,0,0,1,0,0><<<dim3(16,16,4),256,0,stream>>>(qkv2, qkv2+1024, Sbuf, nullptr, qbar2,
          1024,1024,64, 3072,3072,1024, SCALE, z0, Z0,3145728,64, 0,3145728,64, 1048576,0,0);
      softmax_k<-1><<<dim3(1024,4),256,0,stream>>>(Sbuf,Pbf);
      // out = P @ v'avg  (v-bar contributes 0: rows of P sum to 0)
      gemm_k<1,0,0,0,0,0><<<dim3(1,16,4),256,0,stream>>>(Pbf, vavgT, attnout, nullptr, nullptr,
          1024,64,1024, 1024,1024,1024, 1.0f, z0, 1048576,0,0, 0,1048576,65536, 0,1048576,64);
    }
    // proj (f32 out) + LN + residual
    gemm_k<0,0,1,1,0,0><<<dim3(16,32,1),256,0,stream>>>(attnout, Wo+(long)l*1048576, projout, bo+l*1024, nullptr,
        2048,1024,1024, 1024,1024,1024, 1.0f, 0, Z0,0,0, 0,0,0, 0,0,0);
    ln_k<1,0,0><<<2048,256,0,stream>>>(projout, gO+l*1024, bO+l*1024, xc, nullptr);
    // MLP
    ln_k<0,1,0><<<2048,256,0,stream>>>(xc, g2+l*1024, b2+l*1024, nullptr, h2);
    gemm_k<0,0,1,0,0,1><<<dim3(64,32,1),256,0,stream>>>(h2,  Wm1+(long)l*4194304, mid, bm1+l*4096, nullptr,
        2048,4096,1024, 1024,4096,4096, 1.0f, 0, Z0,0,0, 0,0,0, 0,0,0);
    gemm_k<0,0,1,1,1,0><<<dim3(16,32,1),256,0,stream>>>(mid, Wm2+(long)l*4194304, xc,  bm2+l*1024, nullptr,
        2048,1024,4096, 4096,1024,1024, 1.0f, 0, Z0,0,0, 0,0,0, 0,0,0);
  }
  ln_k<0,1,1><<<2048,256,0,stream>>>(xc, gf, bfv, nullptr, (float*)d_out);
}